// Round 1
// baseline (209.118 us; speedup 1.0000x reference)
//
#include <hip/hip_runtime.h>
#include <math.h>

#define BDIM 4096
#define DDIM 128
#define EPSF 1e-12f
#define TI 64
#define TJ 64
#define NSPLIT 16
#define TILES_PER_MAT (BDIM / TJ)          // 64
#define TOTAL_JT (3 * TILES_PER_MAT)       // 192
#define JT_PER_SPLIT (TOTAL_JT / NSPLIT)   // 12
#define FLT_BIG 3.402823466e+38f

// ---------------- Kernel 1: row norms + distance_pos ----------------
// One wave (64 lanes) per row index i: computes a2[i], p2[i], n2[i], dpos[i].
__global__ __launch_bounds__(256) void norms_kernel(
    const float* __restrict__ A, const float* __restrict__ P,
    const float* __restrict__ N, float* __restrict__ a2,
    float* __restrict__ p2, float* __restrict__ n2,
    float* __restrict__ dpos) {
    int wave = (blockIdx.x * blockDim.x + threadIdx.x) >> 6;
    int lane = threadIdx.x & 63;
    if (wave >= BDIM) return;
    const float2 av = *(const float2*)&A[wave * DDIM + lane * 2];
    const float2 pv = *(const float2*)&P[wave * DDIM + lane * 2];
    const float2 nv = *(const float2*)&N[wave * DDIM + lane * 2];
    float sa = av.x * av.x + av.y * av.y;
    float sp = pv.x * pv.x + pv.y * pv.y;
    float sn = nv.x * nv.x + nv.y * nv.y;
    float dx = av.x - pv.x, dy = av.y - pv.y;
    float sd = dx * dx + dy * dy;
    #pragma unroll
    for (int off = 32; off; off >>= 1) {
        sa += __shfl_down(sa, off);
        sp += __shfl_down(sp, off);
        sn += __shfl_down(sn, off);
        sd += __shfl_down(sd, off);
    }
    if (lane == 0) {
        a2[wave] = sa;
        p2[wave] = sp;
        n2[wave] = sn;
        dpos[wave] = sqrtf(fmaxf(sd, EPSF));
    }
}

// ---------------- Kernel 2: tiled pairwise min of squared distances ----------------
// Grid: (64 i-tiles, NSPLIT j-splits). Each block: 256 threads, 4x4 register blocking.
// partial[split*BDIM + i] = min over this split's j-tiles of (a2[i]+y2[j]-2*dot).
__global__ __launch_bounds__(256) void minsq_kernel(
    const float* __restrict__ A, const float* __restrict__ P,
    const float* __restrict__ Nn,
    const float* __restrict__ a2, const float* __restrict__ p2,
    const float* __restrict__ n2,
    float* __restrict__ partial) {
    __shared__ float As[DDIM][TI];  // [k][i] transposed, 32 KB
    __shared__ float Ys[DDIM][TJ];  // [k][j] transposed, 32 KB

    const int iTile = blockIdx.x;
    const int split = blockIdx.y;
    const int i0 = iTile * TI;
    const int tid = threadIdx.x;
    const int r = tid >> 2;   // 0..63: row within tile (for staging)
    const int sub = tid & 3;  // k-quarter (for staging)
    const int tx = tid & 15;  // j-block 0..15
    const int ty = tid >> 4;  // i-block 0..15

    // Stage A tile transposed: As[k][i_local]
    {
        const float* src = A + (size_t)(i0 + r) * DDIM + sub * 32;
        #pragma unroll
        for (int q = 0; q < 8; ++q) {
            float4 v = *(const float4*)(src + q * 4);
            int k = sub * 32 + q * 4;
            As[k + 0][r] = v.x;
            As[k + 1][r] = v.y;
            As[k + 2][r] = v.z;
            As[k + 3][r] = v.w;
        }
    }

    float myA2[4];
    #pragma unroll
    for (int ii = 0; ii < 4; ++ii) myA2[ii] = a2[i0 + ty * 4 + ii];

    float minsq[4] = {FLT_BIG, FLT_BIG, FLT_BIG, FLT_BIG};

    const int jt_lo = split * JT_PER_SPLIT;
    const int jt_hi = jt_lo + JT_PER_SPLIT;
    for (int jt = jt_lo; jt < jt_hi; ++jt) {
        const int m = jt >> 6;        // 0=A, 1=P, 2=N
        const int tc = jt & 63;       // tile column
        const int j0 = tc * TJ;
        const float* Y = (m == 0) ? A : ((m == 1) ? P : Nn);
        const float* y2g = (m == 0) ? a2 : ((m == 1) ? p2 : n2);

        __syncthreads();  // previous iteration's Ys reads done
        {
            const float* src = Y + (size_t)(j0 + r) * DDIM + sub * 32;
            #pragma unroll
            for (int q = 0; q < 8; ++q) {
                float4 v = *(const float4*)(src + q * 4);
                int k = sub * 32 + q * 4;
                Ys[k + 0][r] = v.x;
                Ys[k + 1][r] = v.y;
                Ys[k + 2][r] = v.z;
                Ys[k + 3][r] = v.w;
            }
        }
        __syncthreads();

        float acc[4][4];
        #pragma unroll
        for (int ii = 0; ii < 4; ++ii)
            #pragma unroll
            for (int jj = 0; jj < 4; ++jj) acc[ii][jj] = 0.f;

        #pragma unroll 8
        for (int k = 0; k < DDIM; ++k) {
            float4 av = *(const float4*)&As[k][ty * 4];
            float4 yv = *(const float4*)&Ys[k][tx * 4];
            float aa[4] = {av.x, av.y, av.z, av.w};
            float yy[4] = {yv.x, yv.y, yv.z, yv.w};
            #pragma unroll
            for (int ii = 0; ii < 4; ++ii)
                #pragma unroll
                for (int jj = 0; jj < 4; ++jj)
                    acc[ii][jj] = fmaf(aa[ii], yy[jj], acc[ii][jj]);
        }

        float4 y2v = *(const float4*)&y2g[j0 + tx * 4];
        float y2a[4] = {y2v.x, y2v.y, y2v.z, y2v.w};
        const bool diagTile = (m < 2) && (tc == iTile);
        #pragma unroll
        for (int ii = 0; ii < 4; ++ii) {
            #pragma unroll
            for (int jj = 0; jj < 4; ++jj) {
                float cand = myA2[ii] + y2a[jj] - 2.0f * acc[ii][jj];
                if (diagTile && (ty * 4 + ii == tx * 4 + jj)) cand = FLT_BIG;
                minsq[ii] = fminf(minsq[ii], cand);
            }
        }
    }

    // Reduce across the 16 tx lanes (lane bits 0..3) — stays within the wave.
    #pragma unroll
    for (int off = 1; off < 16; off <<= 1) {
        #pragma unroll
        for (int ii = 0; ii < 4; ++ii)
            minsq[ii] = fminf(minsq[ii], __shfl_xor(minsq[ii], off));
    }
    if (tx == 0) {
        #pragma unroll
        for (int ii = 0; ii < 4; ++ii)
            partial[split * BDIM + i0 + ty * 4 + ii] = minsq[ii];
    }
}

// ---------------- Kernel 3: final loss ----------------
__global__ __launch_bounds__(256) void loss_kernel(
    const float* __restrict__ partial, const float* __restrict__ dpos,
    float* __restrict__ out) {
    __shared__ float red[4];
    float sum = 0.f;
    for (int i = threadIdx.x; i < BDIM; i += 256) {
        float m = FLT_BIG;
        #pragma unroll
        for (int s = 0; s < NSPLIT; ++s) m = fminf(m, partial[s * BDIM + i]);
        float hardest = sqrtf(fmaxf(m, EPSF));
        float x = dpos[i] - hardest;
        // stable logaddexp(0, x) = softplus(x)
        sum += fmaxf(x, 0.f) + log1pf(expf(-fabsf(x)));
    }
    #pragma unroll
    for (int off = 32; off; off >>= 1) sum += __shfl_down(sum, off);
    if ((threadIdx.x & 63) == 0) red[threadIdx.x >> 6] = sum;
    __syncthreads();
    if (threadIdx.x == 0)
        out[0] = (red[0] + red[1] + red[2] + red[3]) * (1.0f / BDIM);
}

extern "C" void kernel_launch(void* const* d_in, const int* in_sizes, int n_in,
                              void* d_out, int out_size, void* d_ws, size_t ws_size,
                              hipStream_t stream) {
    const float* A = (const float*)d_in[0];   // rep_anchor [4096,128]
    const float* P = (const float*)d_in[1];   // rep_pos
    const float* N = (const float*)d_in[2];   // rep_neg

    float* ws = (float*)d_ws;
    float* a2 = ws;                    // 4096
    float* p2 = ws + BDIM;             // 4096
    float* n2 = ws + 2 * BDIM;         // 4096
    float* dpos = ws + 3 * BDIM;       // 4096
    float* partial = ws + 4 * BDIM;    // NSPLIT * 4096

    norms_kernel<<<BDIM / 4, 256, 0, stream>>>(A, P, N, a2, p2, n2, dpos);
    dim3 grid2(TILES_PER_MAT, NSPLIT);
    minsq_kernel<<<grid2, 256, 0, stream>>>(A, P, N, a2, p2, n2, partial);
    loss_kernel<<<1, 256, 0, stream>>>(partial, dpos, (float*)d_out);
}

// Round 3
// 73.592 us; speedup vs baseline: 2.8416x; 2.8416x over previous
//
#include <hip/hip_runtime.h>
#include <math.h>

#define BDIM 4096
#define DDIM 128
#define EPSF 1e-12f
#define TI 64
#define TJ 64
#define NSPLIT 8
#define NSLICE (NSPLIT * 2)                 // separate slice per column-half wave
#define TILES_PER_MAT 64
#define TOTAL_JT (3 * TILES_PER_MAT)        // 192
#define JT_PER_SPLIT (TOTAL_JT / NSPLIT)    // 24
#define FLT_BIG 3.402823466e+38f
#define MATSZ (BDIM * DDIM)                 // 524288

typedef __attribute__((ext_vector_type(8))) short bf16x8;
typedef __attribute__((ext_vector_type(16))) float f32x16;

// global (pre-swizzled per-lane addr) -> linear LDS, 16B/lane
__device__ __forceinline__ void gload_lds16(const void* g, void* l) {
    __builtin_amdgcn_global_load_lds(
        (const __attribute__((address_space(1))) unsigned int*)(uintptr_t)g,
        (__attribute__((address_space(3))) unsigned int*)(unsigned int)(uintptr_t)l,
        16, 0, 0);
}

__device__ __forceinline__ unsigned short f2bf_rn(float x) {
    unsigned int u = __float_as_uint(x);
    unsigned int r = u + 0x7fffu + ((u >> 16) & 1u);
    return (unsigned short)(r >> 16);
}

// ---------------- Kernel 0: f32 -> bf16 hi/lo planes ----------------
__global__ __launch_bounds__(256) void convert_kernel(
    const float* __restrict__ A, const float* __restrict__ P,
    const float* __restrict__ N, ushort* __restrict__ hi,
    ushort* __restrict__ lo) {
    int idx = blockIdx.x * 256 + threadIdx.x;     // float4 granules
    int m = idx >> 17;                            // / 131072
    int off = (idx & 131071) * 4;
    const float* src = (m == 0) ? A : ((m == 1) ? P : N);
    float4 v = *(const float4*)&src[off];
    float xs[4] = {v.x, v.y, v.z, v.w};
    unsigned short hh[4], ll[4];
    #pragma unroll
    for (int c = 0; c < 4; ++c) {
        unsigned short hb = f2bf_rn(xs[c]);
        float hf = __uint_as_float(((unsigned int)hb) << 16);
        hh[c] = hb;
        ll[c] = f2bf_rn(xs[c] - hf);
    }
    ushort4 hv = {hh[0], hh[1], hh[2], hh[3]};
    ushort4 lv = {ll[0], ll[1], ll[2], ll[3]};
    *(ushort4*)&hi[m * MATSZ + off] = hv;
    *(ushort4*)&lo[m * MATSZ + off] = lv;
}

// ---------------- Kernel 1: row norms + distance_pos (f32 exact) ----------------
__global__ __launch_bounds__(256) void norms_kernel(
    const float* __restrict__ A, const float* __restrict__ P,
    const float* __restrict__ N, float* __restrict__ a2,
    float* __restrict__ p2, float* __restrict__ n2,
    float* __restrict__ dpos) {
    int wave = (blockIdx.x * blockDim.x + threadIdx.x) >> 6;
    int lane = threadIdx.x & 63;
    if (wave >= BDIM) return;
    const float2 av = *(const float2*)&A[wave * DDIM + lane * 2];
    const float2 pv = *(const float2*)&P[wave * DDIM + lane * 2];
    const float2 nv = *(const float2*)&N[wave * DDIM + lane * 2];
    float sa = av.x * av.x + av.y * av.y;
    float sp = pv.x * pv.x + pv.y * pv.y;
    float sn = nv.x * nv.x + nv.y * nv.y;
    float dx = av.x - pv.x, dy = av.y - pv.y;
    float sd = dx * dx + dy * dy;
    #pragma unroll
    for (int off = 32; off; off >>= 1) {
        sa += __shfl_down(sa, off);
        sp += __shfl_down(sp, off);
        sn += __shfl_down(sn, off);
        sd += __shfl_down(sd, off);
    }
    if (lane == 0) {
        a2[wave] = sa;
        p2[wave] = sp;
        n2[wave] = sn;
        dpos[wave] = sqrtf(fmaxf(sd, EPSF));
    }
}

// stage one 64x128 bf16 tile (rows g0..g0+63 of matrix `g`) into linear LDS,
// with slot-XOR swizzle applied on the global source address (involution).
__device__ __forceinline__ void stage_tile(const ushort* g, int g0, short* dst,
                                           int w, int lane) {
    int sub = lane >> 4;       // 0..3 (row within 4-row instr span)
    int s = lane & 15;         // 16B slot within row
    #pragma unroll
    for (int q = 0; q < 4; ++q) {
        int r = w * 16 + q * 4 + sub;       // local row 0..63
        int sp = s ^ (r & 7);               // pre-swizzled source slot
        gload_lds16(g + (size_t)(g0 + r) * DDIM + sp * 8,
                    dst + (w * 16 + q * 4) * DDIM);
    }
}

// ---------------- Kernel 2: MFMA min-of-squared-distances ----------------
// grid (64 i-tiles, NSPLIT). 256 thr = 4 waves (2x2 of 32x32 outputs).
__global__ __launch_bounds__(256, 2) void minsq_kernel(
    const ushort* __restrict__ hi, const ushort* __restrict__ lo,
    const float* __restrict__ a2, const float* __restrict__ p2,
    const float* __restrict__ n2, float* __restrict__ partial) {
    __shared__ __align__(16) short Ah[TI * DDIM];
    __shared__ __align__(16) short Al[TI * DDIM];
    __shared__ __align__(16) short Yh[TJ * DDIM];
    __shared__ __align__(16) short Yl[TJ * DDIM];

    const int tid = threadIdx.x;
    const int w = tid >> 6;
    const int lane = tid & 63;
    const int wr = w >> 1, wc = w & 1;
    const int iTile = blockIdx.x;
    const int split = blockIdx.y;
    const int i0 = iTile * TI;

    // stage A tiles (matrix 0 of hi/lo planes)
    {
        int sub = lane >> 4, s = lane & 15;
        #pragma unroll
        for (int q = 0; q < 4; ++q) {
            int r = w * 16 + q * 4 + sub;
            int sp = s ^ (r & 7);
            gload_lds16(hi + (size_t)(i0 + r) * DDIM + sp * 8,
                        Ah + (w * 16 + q * 4) * DDIM);
            gload_lds16(lo + (size_t)(i0 + r) * DDIM + sp * 8,
                        Al + (w * 16 + q * 4) * DDIM);
        }
    }
    // stage first Y tile
    const int jt0 = split * JT_PER_SPLIT;
    {
        int m = jt0 >> 6, tc = jt0 & 63;
        stage_tile(hi + (size_t)m * MATSZ, tc * TJ, Yh, w, lane);
        stage_tile(lo + (size_t)m * MATSZ, tc * TJ, Yl, w, lane);
    }
    __syncthreads();

    // preload this wave's A fragments (rows wr*32 + (lane&31))
    bf16x8 afr[2][8];
    {
        int r = wr * 32 + (lane & 31);
        #pragma unroll
        for (int t = 0; t < 8; ++t) {
            int sl = t * 2 + (lane >> 5);
            int sp = sl ^ (r & 7);
            afr[0][t] = *(const bf16x8*)&Ah[r * DDIM + sp * 8];
            afr[1][t] = *(const bf16x8*)&Al[r * DDIM + sp * 8];
        }
    }
    float a2v[16];
    #pragma unroll
    for (int g = 0; g < 16; ++g) {
        int rloc = (g & 3) + 8 * (g >> 2) + 4 * (lane >> 5);
        a2v[g] = a2[i0 + wr * 32 + rloc];
    }
    float minv[16];
    #pragma unroll
    for (int g = 0; g < 16; ++g) minv[g] = FLT_BIG;

    for (int idx = 0; idx < JT_PER_SPLIT; ++idx) {
        const int jt = jt0 + idx;
        const int m = jt >> 6;
        const int tc = jt & 63;
        const int j0 = tc * TJ;
        const float* y2g = (m == 0) ? a2 : ((m == 1) ? p2 : n2);

        // two accumulator chains for MFMA ILP: hi*hi, and hi*lo + lo*hi
        f32x16 acc1 = {};
        f32x16 acc2 = {};
        {
            int r = wc * 32 + (lane & 31);
            #pragma unroll
            for (int t = 0; t < 8; ++t) {
                int sl = t * 2 + (lane >> 5);
                int sp = sl ^ (r & 7);
                bf16x8 bh = *(const bf16x8*)&Yh[r * DDIM + sp * 8];
                bf16x8 bl = *(const bf16x8*)&Yl[r * DDIM + sp * 8];
                acc1 = __builtin_amdgcn_mfma_f32_32x32x16_bf16(afr[0][t], bh, acc1, 0, 0, 0);
                acc2 = __builtin_amdgcn_mfma_f32_32x32x16_bf16(afr[0][t], bl, acc2, 0, 0, 0);
                acc2 = __builtin_amdgcn_mfma_f32_32x32x16_bf16(afr[1][t], bh, acc2, 0, 0, 0);
            }
        }

        // epilogue: dist^2 = a2 + y2 - 2*dot; diag exclusion; running min
        {
            int col = lane & 31;
            int jg = j0 + wc * 32 + col;
            float y2v = y2g[jg];
            #pragma unroll
            for (int g = 0; g < 16; ++g) {
                int rloc = (g & 3) + 8 * (g >> 2) + 4 * (lane >> 5);
                int ig = i0 + wr * 32 + rloc;
                float dot = acc1[g] + acc2[g];
                float cand = a2v[g] + y2v - 2.0f * dot;
                if (m < 2 && ig == jg) cand = FLT_BIG;
                minv[g] = fminf(minv[g], cand);
            }
        }

        if (idx + 1 < JT_PER_SPLIT) {
            __syncthreads();   // all waves done reading Yh/Yl
            int jn = jt + 1;
            int mn = jn >> 6, tcn = jn & 63;
            stage_tile(hi + (size_t)mn * MATSZ, tcn * TJ, Yh, w, lane);
            stage_tile(lo + (size_t)mn * MATSZ, tcn * TJ, Yl, w, lane);
            __syncthreads();   // staging drained (compiler emits vmcnt(0))
        }
    }

    // reduce min over the 32 columns (stays within 32-lane halves)
    #pragma unroll
    for (int off = 1; off < 32; off <<= 1) {
        #pragma unroll
        for (int g = 0; g < 16; ++g)
            minv[g] = fminf(minv[g], __shfl_xor(minv[g], off));
    }
    // each column-half wave (wc) writes its own slice — no cross-wave clobber
    if ((lane & 31) == 0) {
        #pragma unroll
        for (int g = 0; g < 16; ++g) {
            int rloc = (g & 3) + 8 * (g >> 2) + 4 * (lane >> 5);
            partial[(split * 2 + wc) * BDIM + i0 + wr * 32 + rloc] = minv[g];
        }
    }
}

// ---------------- Kernel 3: final loss ----------------
__global__ __launch_bounds__(256) void loss_kernel(
    const float* __restrict__ partial, const float* __restrict__ dpos,
    float* __restrict__ out) {
    __shared__ float red[4];
    float sum = 0.f;
    for (int i = threadIdx.x; i < BDIM; i += 256) {
        float m = FLT_BIG;
        #pragma unroll
        for (int s = 0; s < NSLICE; ++s) m = fminf(m, partial[s * BDIM + i]);
        float hardest = sqrtf(fmaxf(m, EPSF));
        float x = dpos[i] - hardest;
        sum += fmaxf(x, 0.f) + log1pf(expf(-fabsf(x)));
    }
    #pragma unroll
    for (int off = 32; off; off >>= 1) sum += __shfl_down(sum, off);
    if ((threadIdx.x & 63) == 0) red[threadIdx.x >> 6] = sum;
    __syncthreads();
    if (threadIdx.x == 0)
        out[0] = (red[0] + red[1] + red[2] + red[3]) * (1.0f / BDIM);
}

extern "C" void kernel_launch(void* const* d_in, const int* in_sizes, int n_in,
                              void* d_out, int out_size, void* d_ws, size_t ws_size,
                              hipStream_t stream) {
    const float* A = (const float*)d_in[0];
    const float* P = (const float*)d_in[1];
    const float* N = (const float*)d_in[2];

    float* ws = (float*)d_ws;
    float* a2 = ws;                         // 4096
    float* p2 = ws + BDIM;                  // 4096
    float* n2 = ws + 2 * BDIM;              // 4096
    float* dpos = ws + 3 * BDIM;            // 4096
    float* partial = ws + 4 * BDIM;         // NSLICE * 4096
    ushort* hi = (ushort*)(ws + (4 + NSLICE) * BDIM);   // 3*524288 bf16
    ushort* lo = hi + 3 * (size_t)MATSZ;                // 3*524288 bf16

    convert_kernel<<<1536, 256, 0, stream>>>(A, P, N, hi, lo);
    norms_kernel<<<BDIM / 4, 256, 0, stream>>>(A, P, N, a2, p2, n2, dpos);
    dim3 grid2(TILES_PER_MAT, NSPLIT);
    minsq_kernel<<<grid2, 256, 0, stream>>>(hi, lo, a2, p2, n2, partial);
    loss_kernel<<<1, 256, 0, stream>>>(partial, dpos, (float*)d_out);
}

// Round 4
// 35.650 us; speedup vs baseline: 5.8659x; 2.0643x over previous
//
#include <hip/hip_runtime.h>
#include <math.h>

#define BDIM 4096
#define DDIM 128
#define EPSF 1e-12f
#define TI 128
#define TJ 64
#define NSPLIT 16
#define NSLICE (NSPLIT * 2)                 // one slice per column-half wave
#define ITILES (BDIM / TI)                  // 32
#define TILES_PER_MAT (BDIM / TJ)           // 64
#define TOTAL_JT (3 * TILES_PER_MAT)        // 192
#define JT_PER_SPLIT (TOTAL_JT / NSPLIT)    // 12
#define FLT_BIG 3.402823466e+38f
#define MATSZ (BDIM * DDIM)                 // 524288

typedef __attribute__((ext_vector_type(8))) _Float16 f16x8;
typedef __attribute__((ext_vector_type(16))) float f32x16;

// global (pre-swizzled per-lane addr) -> linear LDS, 16B/lane
__device__ __forceinline__ void gload_lds16(const void* g, void* l) {
    __builtin_amdgcn_global_load_lds(
        (const __attribute__((address_space(1))) unsigned int*)(uintptr_t)g,
        (__attribute__((address_space(3))) unsigned int*)(unsigned int)(uintptr_t)l,
        16, 0, 0);
}

__device__ __forceinline__ unsigned int pack2h(float x, float y) {
    _Float16 hx = (_Float16)x, hy = (_Float16)y;
    unsigned short ux, uy;
    __builtin_memcpy(&ux, &hx, 2);
    __builtin_memcpy(&uy, &hy, 2);
    return (unsigned int)ux | ((unsigned int)uy << 16);
}

// ---------------- Kernel 0: fused fp16 convert + row norms + distance_pos ----
// One wave per row i: packs A/P/N row to fp16 and computes a2,p2,n2,dpos (f32).
__global__ __launch_bounds__(256) void prep_kernel(
    const float* __restrict__ A, const float* __restrict__ P,
    const float* __restrict__ N, ushort* __restrict__ Xf,
    float* __restrict__ a2, float* __restrict__ p2,
    float* __restrict__ n2, float* __restrict__ dpos) {
    int row = (blockIdx.x * blockDim.x + threadIdx.x) >> 6;
    int lane = threadIdx.x & 63;
    if (row >= BDIM) return;
    const float2 av = *(const float2*)&A[row * DDIM + lane * 2];
    const float2 pv = *(const float2*)&P[row * DDIM + lane * 2];
    const float2 nv = *(const float2*)&N[row * DDIM + lane * 2];
    *(unsigned int*)&Xf[0 * MATSZ + row * DDIM + lane * 2] = pack2h(av.x, av.y);
    *(unsigned int*)&Xf[1 * MATSZ + row * DDIM + lane * 2] = pack2h(pv.x, pv.y);
    *(unsigned int*)&Xf[2 * MATSZ + row * DDIM + lane * 2] = pack2h(nv.x, nv.y);
    float sa = av.x * av.x + av.y * av.y;
    float sp = pv.x * pv.x + pv.y * pv.y;
    float sn = nv.x * nv.x + nv.y * nv.y;
    float dx = av.x - pv.x, dy = av.y - pv.y;
    float sd = dx * dx + dy * dy;
    #pragma unroll
    for (int off = 32; off; off >>= 1) {
        sa += __shfl_down(sa, off);
        sp += __shfl_down(sp, off);
        sn += __shfl_down(sn, off);
        sd += __shfl_down(sd, off);
    }
    if (lane == 0) {
        a2[row] = sa;
        p2[row] = sp;
        n2[row] = sn;
        dpos[row] = sqrtf(fmaxf(sd, EPSF));
    }
}

// stage one 64x128 fp16 tile (rows j0..j0+63 of matrix plane g) into linear
// LDS; XOR-16-slot swizzle applied on the global source address (involution).
__device__ __forceinline__ void stage_Y(const ushort* g, int j0, ushort* dst,
                                        int w, int lane) {
    int sub = lane >> 4;       // row within 4-row instr span
    int s = lane & 15;         // 16B slot within row
    #pragma unroll
    for (int q = 0; q < 4; ++q) {
        int r = w * 16 + q * 4 + sub;       // local row 0..63
        int sp = s ^ (r & 15);              // pre-swizzled source slot
        gload_lds16(g + (size_t)(j0 + r) * DDIM + sp * 8,
                    dst + (w * 16 + q * 4) * DDIM);
    }
}

// ---------------- Kernel 1: fp16 MFMA min of (y2/2 - dot) ----------------
// grid (32 i-tiles, NSPLIT). 256 thr = 4 waves; each wave outputs 64x32
// (2 acc chains sharing each B fragment -> LDS:MFMA = 1:2).
__global__ __launch_bounds__(256, 2) void minsq_kernel(
    const ushort* __restrict__ Xf,
    const float* __restrict__ a2, const float* __restrict__ p2,
    const float* __restrict__ n2, float* __restrict__ partial) {
    __shared__ __align__(16) ushort Ah[TI * DDIM];     // 32 KB
    __shared__ __align__(16) ushort Yh[2][TJ * DDIM];  // 2 x 16 KB

    const int tid = threadIdx.x;
    const int w = tid >> 6;
    const int lane = tid & 63;
    const int rg = w >> 1;    // 64-row group 0..1
    const int ch = w & 1;     // 32-col half 0..1
    const int iTile = blockIdx.x;
    const int split = blockIdx.y;
    const int i0 = iTile * TI;

    // stage A rows [i0, i0+128)
    {
        int sub = lane >> 4, s = lane & 15;
        #pragma unroll
        for (int q = 0; q < 8; ++q) {
            int r = w * 32 + q * 4 + sub;
            int sp = s ^ (r & 15);
            gload_lds16(Xf + (size_t)(i0 + r) * DDIM + sp * 8,
                        Ah + (w * 32 + q * 4) * DDIM);
        }
    }
    // stage first Y tile
    const int jt0 = split * JT_PER_SPLIT;
    stage_Y(Xf + (size_t)(jt0 >> 6) * MATSZ, (jt0 & 63) * TJ, Yh[0], w, lane);
    __syncthreads();

    // preload this wave's A fragments: 2 row-blocks x 8 k-slices
    f16x8 afr[2][8];
    #pragma unroll
    for (int rb = 0; rb < 2; ++rb) {
        int r = rg * 64 + rb * 32 + (lane & 31);
        #pragma unroll
        for (int t = 0; t < 8; ++t) {
            int sl = t * 2 + (lane >> 5);
            int sp = sl ^ (r & 15);
            afr[rb][t] = *(const f16x8*)&Ah[r * DDIM + sp * 8];
        }
    }

    float minv[2][16];
    #pragma unroll
    for (int rb = 0; rb < 2; ++rb)
        #pragma unroll
        for (int g = 0; g < 16; ++g) minv[rb][g] = FLT_BIG;

    for (int idx = 0; idx < JT_PER_SPLIT; ++idx) {
        const int jt = jt0 + idx;
        const int m = jt >> 6;
        const int tc = jt & 63;
        const int cur = idx & 1;

        // prefetch next tile into the other buffer (stays in flight over MFMA)
        if (idx + 1 < JT_PER_SPLIT) {
            int jn = jt + 1;
            stage_Y(Xf + (size_t)(jn >> 6) * MATSZ, (jn & 63) * TJ,
                    Yh[cur ^ 1], w, lane);
        }

        f32x16 acc0 = {};
        f32x16 acc1 = {};
        {
            int r = ch * 32 + (lane & 31);
            #pragma unroll
            for (int t = 0; t < 8; ++t) {
                int sl = t * 2 + (lane >> 5);
                int sp = sl ^ (r & 15);
                f16x8 b = *(const f16x8*)&Yh[cur][r * DDIM + sp * 8];
                acc0 = __builtin_amdgcn_mfma_f32_32x32x16_f16(afr[0][t], b, acc0, 0, 0, 0);
                acc1 = __builtin_amdgcn_mfma_f32_32x32x16_f16(afr[1][t], b, acc1, 0, 0, 0);
            }
        }

        // epilogue: track min of (y2/2 - dot); diag exclusion on A/P mats
        const float* y2g = (m == 0) ? a2 : ((m == 1) ? p2 : n2);
        const int jg = tc * TJ + ch * 32 + (lane & 31);
        const float y2h = 0.5f * y2g[jg];
        if (m < 2 && (tc >> 1) == iTile) {
            #pragma unroll
            for (int rb = 0; rb < 2; ++rb) {
                #pragma unroll
                for (int g = 0; g < 16; ++g) {
                    int rloc = (g & 3) + 8 * (g >> 2) + 4 * (lane >> 5);
                    int ig = i0 + rg * 64 + rb * 32 + rloc;
                    float d = (rb == 0) ? acc0[g] : acc1[g];
                    float cand = y2h - d;
                    if (ig == jg) cand = FLT_BIG;
                    minv[rb][g] = fminf(minv[rb][g], cand);
                }
            }
        } else {
            #pragma unroll
            for (int g = 0; g < 16; ++g) {
                minv[0][g] = fminf(minv[0][g], y2h - acc0[g]);
                minv[1][g] = fminf(minv[1][g], y2h - acc1[g]);
            }
        }
        __syncthreads();   // drains prefetch (vmcnt) + protects Yh[cur]
    }

    // min over the 32 columns (within each 32-lane half)
    #pragma unroll
    for (int off = 1; off < 32; off <<= 1) {
        #pragma unroll
        for (int rb = 0; rb < 2; ++rb)
            #pragma unroll
            for (int g = 0; g < 16; ++g)
                minv[rb][g] = fminf(minv[rb][g], __shfl_xor(minv[rb][g], off));
    }
    if ((lane & 31) == 0) {
        int hi = lane >> 5;
        #pragma unroll
        for (int rb = 0; rb < 2; ++rb) {
            #pragma unroll
            for (int g = 0; g < 16; ++g) {
                int rloc = (g & 3) + 8 * (g >> 2) + 4 * hi;
                int ig = i0 + rg * 64 + rb * 32 + rloc;
                partial[(split * 2 + ch) * BDIM + ig] = minv[rb][g];
            }
        }
    }
}

// ---------------- Kernel 2a: per-row loss, 16-block partial sums ------------
__global__ __launch_bounds__(256) void lossA_kernel(
    const float* __restrict__ partial, const float* __restrict__ a2,
    const float* __restrict__ dpos, float* __restrict__ bsum) {
    __shared__ float red[4];
    int i = blockIdx.x * 256 + threadIdx.x;
    float mv = FLT_BIG;
    #pragma unroll
    for (int s = 0; s < NSLICE; ++s) mv = fminf(mv, partial[s * BDIM + i]);
    float h2 = a2[i] + 2.0f * mv;
    float hardest = sqrtf(fmaxf(h2, EPSF));
    float x = dpos[i] - hardest;
    float sum = fmaxf(x, 0.f) + log1pf(expf(-fabsf(x)));
    #pragma unroll
    for (int off = 32; off; off >>= 1) sum += __shfl_down(sum, off);
    if ((threadIdx.x & 63) == 0) red[threadIdx.x >> 6] = sum;
    __syncthreads();
    if (threadIdx.x == 0)
        bsum[blockIdx.x] = red[0] + red[1] + red[2] + red[3];
}

// ---------------- Kernel 2b: final scalar ----------------
__global__ void lossB_kernel(const float* __restrict__ bsum,
                             float* __restrict__ out) {
    float v = (threadIdx.x < 16) ? bsum[threadIdx.x] : 0.f;
    #pragma unroll
    for (int off = 32; off; off >>= 1) v += __shfl_down(v, off);
    if (threadIdx.x == 0) out[0] = v * (1.0f / BDIM);
}

extern "C" void kernel_launch(void* const* d_in, const int* in_sizes, int n_in,
                              void* d_out, int out_size, void* d_ws, size_t ws_size,
                              hipStream_t stream) {
    const float* A = (const float*)d_in[0];
    const float* P = (const float*)d_in[1];
    const float* N = (const float*)d_in[2];

    float* ws = (float*)d_ws;
    float* a2 = ws;                          // 4096
    float* p2 = ws + BDIM;                   // 4096
    float* n2 = ws + 2 * BDIM;               // 4096
    float* dpos = ws + 3 * BDIM;             // 4096
    float* bsum = ws + 4 * BDIM;             // 64 (16 used)
    float* partial = ws + 4 * BDIM + 64;     // NSLICE * 4096
    ushort* Xf = (ushort*)(partial + (size_t)NSLICE * BDIM);  // 3*524288 fp16

    prep_kernel<<<BDIM / 4, 256, 0, stream>>>(A, P, N, Xf, a2, p2, n2, dpos);
    dim3 grid2(ITILES, NSPLIT);
    minsq_kernel<<<grid2, 256, 0, stream>>>(Xf, a2, p2, n2, partial);
    lossA_kernel<<<16, 256, 0, stream>>>(partial, a2, dpos, bsum);
    lossB_kernel<<<1, 64, 0, stream>>>(bsum, (float*)d_out);
}

// Round 5
// 35.576 us; speedup vs baseline: 5.8781x; 1.0021x over previous
//
#include <hip/hip_runtime.h>
#include <math.h>

#define BDIM 4096
#define DDIM 128
#define EPSF 1e-12f
#define TI 128
#define TJ 64
#define NSPLIT 16
#define NSLICE (NSPLIT * 2)                 // one slice per column-half wave
#define ITILES (BDIM / TI)                  // 32
#define JT 12                               // tiles per split (16*12 = 192 total)
#define FLT_BIG 3.402823466e+38f
#define MATSZ (BDIM * DDIM)                 // 524288
#define YBUF (TJ * DDIM)                    // 8192 ushorts = 16 KB

typedef __attribute__((ext_vector_type(8))) _Float16 f16x8;
typedef __attribute__((ext_vector_type(16))) float f32x16;

// global (pre-swizzled per-lane addr) -> linear LDS, 16B/lane
__device__ __forceinline__ void gload_lds16(const void* g, void* l) {
    __builtin_amdgcn_global_load_lds(
        (const __attribute__((address_space(1))) unsigned int*)(uintptr_t)g,
        (__attribute__((address_space(3))) unsigned int*)(unsigned int)(uintptr_t)l,
        16, 0, 0);
}

__device__ __forceinline__ unsigned int pack2h(float x, float y) {
    _Float16 hx = (_Float16)x, hy = (_Float16)y;
    unsigned short ux, uy;
    __builtin_memcpy(&ux, &hx, 2);
    __builtin_memcpy(&uy, &hy, 2);
    return (unsigned int)ux | ((unsigned int)uy << 16);
}

// ---------------- Kernel 0: fused fp16 convert + row norms + distance_pos ----
__global__ __launch_bounds__(256) void prep_kernel(
    const float* __restrict__ A, const float* __restrict__ P,
    const float* __restrict__ N, ushort* __restrict__ Xf,
    float* __restrict__ a2, float* __restrict__ p2,
    float* __restrict__ n2, float* __restrict__ dpos) {
    int row = (blockIdx.x * blockDim.x + threadIdx.x) >> 6;
    int lane = threadIdx.x & 63;
    if (row >= BDIM) return;
    const float2 av = *(const float2*)&A[row * DDIM + lane * 2];
    const float2 pv = *(const float2*)&P[row * DDIM + lane * 2];
    const float2 nv = *(const float2*)&N[row * DDIM + lane * 2];
    *(unsigned int*)&Xf[0 * MATSZ + row * DDIM + lane * 2] = pack2h(av.x, av.y);
    *(unsigned int*)&Xf[1 * MATSZ + row * DDIM + lane * 2] = pack2h(pv.x, pv.y);
    *(unsigned int*)&Xf[2 * MATSZ + row * DDIM + lane * 2] = pack2h(nv.x, nv.y);
    float sa = av.x * av.x + av.y * av.y;
    float sp = pv.x * pv.x + pv.y * pv.y;
    float sn = nv.x * nv.x + nv.y * nv.y;
    float dx = av.x - pv.x, dy = av.y - pv.y;
    float sd = dx * dx + dy * dy;
    #pragma unroll
    for (int off = 32; off; off >>= 1) {
        sa += __shfl_down(sa, off);
        sp += __shfl_down(sp, off);
        sn += __shfl_down(sn, off);
        sd += __shfl_down(sd, off);
    }
    if (lane == 0) {
        a2[row] = sa;
        p2[row] = sp;
        n2[row] = sn;
        dpos[row] = sqrtf(fmaxf(sd, EPSF));
    }
}

// stage one 64x128 fp16 tile into a linear LDS buffer; XOR-16-slot swizzle on
// the global source address (involution). 4 gload_lds per wave.
__device__ __forceinline__ void stage_Y(const ushort* g, int j0, ushort* dst,
                                        int w, int lane) {
    int sub = lane >> 4;
    int s = lane & 15;
    #pragma unroll
    for (int q = 0; q < 4; ++q) {
        int r = w * 16 + q * 4 + sub;
        int sp = s ^ (r & 15);
        gload_lds16(g + (size_t)(j0 + r) * DDIM + sp * 8,
                    dst + (w * 16 + q * 4) * DDIM);
    }
}

// ---------------- Kernel 1: fp16 MFMA min of (y2/2 - dot) ----------------
// grid (32 i-tiles, NSPLIT). 4 waves; wave = 64 rows x 32 cols (2 acc chains
// share each B fragment). 4 rotating Y buffers (A region reused), counted
// vmcnt, raw barriers, setprio around MFMA.
__global__ __launch_bounds__(256, 2) void minsq_kernel(
    const ushort* __restrict__ Xf,
    const float* __restrict__ a2, const float* __restrict__ p2,
    const float* __restrict__ n2, float* __restrict__ partial) {
    __shared__ __align__(16) ushort pool[4][YBUF];     // 64 KB total
    ushort* const base = &pool[0][0];

    const int tid = threadIdx.x;
    const int w = tid >> 6;
    const int lane = tid & 63;
    const int rg = w >> 1;    // 64-row group
    const int ch = w & 1;     // 32-col half
    const int iTile = blockIdx.x;
    const int split = blockIdx.y;
    const int i0 = iTile * TI;
    const int jt0 = split * JT;
    const int sub = lane >> 4, s = lane & 15;

    // stage A rows [i0, i0+128) into pool[0..1] (A region; freed after preload)
    #pragma unroll
    for (int q = 0; q < 8; ++q) {
        int r = w * 32 + q * 4 + sub;
        int sp = s ^ (r & 15);
        gload_lds16(Xf + (size_t)(i0 + r) * DDIM + sp * 8,
                    base + (w * 32 + q * 4) * DDIM);
    }
    // stage Y tiles t0 -> pool[2], t1 -> pool[3]
    stage_Y(Xf + (size_t)(jt0 >> 6) * MATSZ, (jt0 & 63) * TJ, base + 2 * YBUF, w, lane);
    stage_Y(Xf + (size_t)((jt0 + 1) >> 6) * MATSZ, ((jt0 + 1) & 63) * TJ,
            base + 3 * YBUF, w, lane);

    asm volatile("s_waitcnt vmcnt(8)" ::: "memory");   // my A loads done
    __builtin_amdgcn_s_barrier();                      // everyone's A done
    __builtin_amdgcn_sched_barrier(0);

    // preload this wave's A fragments: 2 row-blocks x 8 k-slices (64 VGPR)
    f16x8 afr[2][8];
    #pragma unroll
    for (int rb = 0; rb < 2; ++rb) {
        int r = rg * 64 + rb * 32 + (lane & 31);
        #pragma unroll
        for (int t = 0; t < 8; ++t) {
            int sl = t * 2 + (lane >> 5);
            int sp = sl ^ (r & 15);
            afr[rb][t] = *(const f16x8*)&base[r * DDIM + sp * 8];
        }
    }
    // preload per-tile y2/2 (removes global loads from the main loop)
    float y2h[JT];
    #pragma unroll
    for (int t = 0; t < JT; ++t) {
        int jt = jt0 + t, m = jt >> 6, tc = jt & 63;
        const float* y2g = (m == 0) ? a2 : ((m == 1) ? p2 : n2);
        y2h[t] = 0.5f * y2g[tc * TJ + ch * 32 + (lane & 31)];
    }
    asm volatile("s_waitcnt lgkmcnt(0)" ::: "memory"); // A-frag reads done
    __builtin_amdgcn_sched_barrier(0);
    __builtin_amdgcn_s_barrier();                      // pool[0..1] reusable
    __builtin_amdgcn_sched_barrier(0);

    float minv[2][16];
    #pragma unroll
    for (int rb = 0; rb < 2; ++rb)
        #pragma unroll
        for (int g = 0; g < 16; ++g) minv[rb][g] = FLT_BIG;

    #pragma unroll
    for (int idx = 0; idx < JT; ++idx) {
        // prefetch tile idx+2 into buffer (idx&3) — stays in flight over MFMA
        if (idx + 2 < JT) {
            int jn = jt0 + idx + 2;
            stage_Y(Xf + (size_t)(jn >> 6) * MATSZ, (jn & 63) * TJ,
                    base + (idx & 3) * YBUF, w, lane);
        }
        // counted vmcnt: ensure tile idx's 4 loads done, keep 8 in flight
        if (idx < JT - 2)       asm volatile("s_waitcnt vmcnt(8)" ::: "memory");
        else if (idx == JT - 2) asm volatile("s_waitcnt vmcnt(4)" ::: "memory");
        else                    asm volatile("s_waitcnt vmcnt(0)" ::: "memory");
        __builtin_amdgcn_s_barrier();
        __builtin_amdgcn_sched_barrier(0);

        const ushort* bufY = base + ((idx + 2) & 3) * YBUF;
        f32x16 acc0 = {};
        f32x16 acc1 = {};
        {
            int r = ch * 32 + (lane & 31);
            __builtin_amdgcn_s_setprio(1);
            #pragma unroll
            for (int t = 0; t < 8; ++t) {
                int sl = t * 2 + (lane >> 5);
                int sp = sl ^ (r & 15);
                f16x8 b = *(const f16x8*)&bufY[r * DDIM + sp * 8];
                acc0 = __builtin_amdgcn_mfma_f32_32x32x16_f16(afr[0][t], b, acc0, 0, 0, 0);
                acc1 = __builtin_amdgcn_mfma_f32_32x32x16_f16(afr[1][t], b, acc1, 0, 0, 0);
            }
            __builtin_amdgcn_s_setprio(0);
        }

        // epilogue: running min of (y2/2 - dot); diag exclusion on A/P mats
        {
            int jt = jt0 + idx, m = jt >> 6, tc = jt & 63;
            float yh = y2h[idx];
            if (m < 2 && (tc >> 1) == iTile) {
                int jg = tc * TJ + ch * 32 + (lane & 31);
                #pragma unroll
                for (int rb = 0; rb < 2; ++rb) {
                    #pragma unroll
                    for (int g = 0; g < 16; ++g) {
                        int rloc = (g & 3) + 8 * (g >> 2) + 4 * (lane >> 5);
                        int ig = i0 + rg * 64 + rb * 32 + rloc;
                        float d = (rb == 0) ? acc0[g] : acc1[g];
                        float cand = yh - d;
                        if (ig == jg) cand = FLT_BIG;
                        minv[rb][g] = fminf(minv[rb][g], cand);
                    }
                }
            } else {
                #pragma unroll
                for (int g = 0; g < 16; ++g) {
                    minv[0][g] = fminf(minv[0][g], yh - acc0[g]);
                    minv[1][g] = fminf(minv[1][g], yh - acc1[g]);
                }
            }
        }
    }

    // min over the 32 columns (within each 32-lane half)
    #pragma unroll
    for (int off = 1; off < 32; off <<= 1) {
        #pragma unroll
        for (int rb = 0; rb < 2; ++rb)
            #pragma unroll
            for (int g = 0; g < 16; ++g)
                minv[rb][g] = fminf(minv[rb][g], __shfl_xor(minv[rb][g], off));
    }
    // transposed partial layout: partial[row][slice]
    if ((lane & 31) == 0) {
        int hi = lane >> 5;
        int slice = split * 2 + ch;
        #pragma unroll
        for (int rb = 0; rb < 2; ++rb) {
            #pragma unroll
            for (int g = 0; g < 16; ++g) {
                int rloc = (g & 3) + 8 * (g >> 2) + 4 * hi;
                int ig = i0 + rg * 64 + rb * 32 + rloc;
                partial[(size_t)ig * NSLICE + slice] = minv[rb][g];
            }
        }
    }
}

// ---------------- Kernel 2a: per-row loss, 16-block partial sums ------------
__global__ __launch_bounds__(256) void lossA_kernel(
    const float* __restrict__ partial, const float* __restrict__ a2,
    const float* __restrict__ dpos, float* __restrict__ bsum) {
    __shared__ float red[4];
    int i = blockIdx.x * 256 + threadIdx.x;
    const float4* pr = (const float4*)&partial[(size_t)i * NSLICE];
    float mv = FLT_BIG;
    #pragma unroll
    for (int q = 0; q < NSLICE / 4; ++q) {
        float4 v = pr[q];
        mv = fminf(mv, fminf(fminf(v.x, v.y), fminf(v.z, v.w)));
    }
    float h2 = a2[i] + 2.0f * mv;
    float hardest = sqrtf(fmaxf(h2, EPSF));
    float x = dpos[i] - hardest;
    float sum = fmaxf(x, 0.f) + log1pf(expf(-fabsf(x)));
    #pragma unroll
    for (int off = 32; off; off >>= 1) sum += __shfl_down(sum, off);
    if ((threadIdx.x & 63) == 0) red[threadIdx.x >> 6] = sum;
    __syncthreads();
    if (threadIdx.x == 0)
        bsum[blockIdx.x] = red[0] + red[1] + red[2] + red[3];
}

// ---------------- Kernel 2b: final scalar ----------------
__global__ void lossB_kernel(const float* __restrict__ bsum,
                             float* __restrict__ out) {
    float v = (threadIdx.x < 16) ? bsum[threadIdx.x] : 0.f;
    #pragma unroll
    for (int off = 32; off; off >>= 1) v += __shfl_down(v, off);
    if (threadIdx.x == 0) out[0] = v * (1.0f / BDIM);
}

extern "C" void kernel_launch(void* const* d_in, const int* in_sizes, int n_in,
                              void* d_out, int out_size, void* d_ws, size_t ws_size,
                              hipStream_t stream) {
    const float* A = (const float*)d_in[0];
    const float* P = (const float*)d_in[1];
    const float* N = (const float*)d_in[2];

    float* ws = (float*)d_ws;
    float* a2 = ws;                          // 4096
    float* p2 = ws + BDIM;                   // 4096
    float* n2 = ws + 2 * BDIM;               // 4096
    float* dpos = ws + 3 * BDIM;             // 4096
    float* bsum = ws + 4 * BDIM;             // 64 (16 used)
    float* partial = ws + 4 * BDIM + 64;     // BDIM * NSLICE (transposed)
    ushort* Xf = (ushort*)(partial + (size_t)NSLICE * BDIM);  // 3*524288 fp16

    prep_kernel<<<BDIM / 4, 256, 0, stream>>>(A, P, N, Xf, a2, p2, n2, dpos);
    dim3 grid2(ITILES, NSPLIT);
    minsq_kernel<<<grid2, 256, 0, stream>>>(Xf, a2, p2, n2, partial);
    lossA_kernel<<<16, 256, 0, stream>>>(partial, a2, dpos, bsum);
    lossB_kernel<<<1, 64, 0, stream>>>(bsum, (float*)d_out);
}